// Round 5
// baseline (310.506 us; speedup 1.0000x reference)
//
#include <hip/hip_runtime.h>

typedef __attribute__((ext_vector_type(4))) float float4v;

#define NBLK 2048

// Persistent 2048 blocks x 128 threads, 4 windows each, double-buffered LDS
// staging via global_load_lds (16B), counted s_waitcnt vmcnt(6) + raw barriers
// (prefetch stays in flight across the barrier). Changes vs round 4, all aimed
// at the VGPR/LDS occupancy caps that keep the kernel latency-bound:
//  - LDS stages ONLY the K/V tensors g,b,ir (r is never K/V): 12 KB/window,
//    24 KB double-buffered -> 6 blocks/CU (was 32 KB -> 5).
//  - Q is read directly from global per-thread (same lines the DMA just
//    fetched -> L2-hot; within-block reuse, unlike round 1's failure mode).
//  - LN-param hoist dropped (-64 VGPR; params are 8 KB, permanently L1-hot).
//  - Plain strided stores (round-0-proven clean WRITE in this structure;
//    the LDS transpose scratch is gone).
__global__ __launch_bounds__(128, 4) void cattn_kernel(
    const float* __restrict__ rr, const float* __restrict__ gg,
    const float* __restrict__ bb, const float* __restrict__ ii,
    const float* __restrict__ w0, const float* __restrict__ b0,
    const float* __restrict__ w1, const float* __restrict__ b1,
    const float* __restrict__ w2, const float* __restrict__ b2,
    const float* __restrict__ w3, const float* __restrict__ b3,
    float* __restrict__ out)
{
    __shared__ float sm[2 * 3072];           // two 12 KB K/V buffers (g,b,ir)
    float4v* SM4 = (float4v*)sm;

    const int t   = threadIdx.x;
    const int wvi = t >> 6;                  // wave 0/1
    const int l   = t & 63;
    const int c4g = l ^ ((l >> 3) & 7);      // swizzled global chunk for staging

    // compute-lane mapping
    const int vloc = l >> 5;
    const int v    = (wvi << 1) | vloc;      // variant 0..3
    const int tok  = (l >> 3) & 3;           // query token 0..3
    const int h    = l & 7;                  // head 0..7
    const int ksl  = (v == 3) ? 0 : v;       // staged K/V slot: g,b,ir,g -> 0,1,2,0

    const float* srcs[4] = { rr, gg, bb, ii };

    // LN param bases (loads happen in the epilogue; L1-hot)
    const float* lwr = ((v & 2) ? ((v & 1) ? w3 : w2) : ((v & 1) ? w1 : w0)) + h * 32;
    const float* lbr = ((v & 2) ? ((v & 1) ? b3 : b2) : ((v & 1) ? b1 : b0)) + h * 32;

    // async stage g,b,ir of one window (12 KB) into buffer `buf`: 6 loads/wave
    auto issue = [&](int buf, int wid) {
        const int bi  = wid >> 10;
        const int rem = wid & 1023;
        const int y0  = (rem >> 5) << 1;
        const int x0  = (rem & 31) << 1;
        #pragma unroll
        for (int kk = 0; kk < 6; ++kk) {
            const int m    = wvi * 6 + kk;   // 0..11 ; wave-uniform per kk
            const int tIdx = m >> 2;         // 0..2 -> g,b,ir
            const int dy   = (m >> 1) & 1;
            const int dx   = m & 1;
            const float* g = srcs[tIdx + 1]
                + (((size_t)(bi * 64 + y0 + dy)) * 64 + (size_t)(x0 + dx)) * 256
                + (size_t)(c4g << 2);
            float* ldst = sm + buf * 3072 + m * 256;
            __builtin_amdgcn_global_load_lds(
                (const __attribute__((address_space(1))) void*)g,
                (__attribute__((address_space(3))) void*)ldst,
                16, 0, 0);
        }
    };

    int wid = blockIdx.x;                    // 4 windows: wid, +2048, +4096, +6144
    issue(0, wid);
    int cur = 0;

    #pragma unroll
    for (int it = 0; it < 4; ++it, wid += NBLK) {
        const int bi  = wid >> 10;
        const int rem = wid & 1023;
        const int y0  = (rem >> 5) << 1;
        const int x0  = (rem & 31) << 1;
        const int dy  = tok >> 1, dx = tok & 1;
        const size_t rowoff =
            (((size_t)(bi * 64 + y0 + dy)) * 64 + (size_t)(x0 + dx)) * 256;

        // Q loads from global, issued BEFORE the prefetch so the counted wait
        // below retires them while keeping the prefetch in flight.
        const float* qp = srcs[v] + rowoff + (size_t)(h * 32);
        float4v qc[8];
        #pragma unroll
        for (int j = 0; j < 8; ++j) qc[j] = *(const float4v*)(qp + j * 4);

        // prefetch next window, then wait with exactly the 6 new loads
        // outstanding: retires Q loads, the current buffer's staging (issued
        // one full iteration ago) and old epilogue stores.
        if (it < 3) {
            issue(cur ^ 1, wid + NBLK);
            asm volatile("s_waitcnt vmcnt(6)");
        } else {
            asm volatile("s_waitcnt vmcnt(0)");
        }
        __builtin_amdgcn_s_barrier();        // other wave's staging also done
        __builtin_amdgcn_sched_barrier(0);

        // ---------- compute window `wid` from buf[cur] ----------
        const int kbase = (cur ? 768 : 0) + ksl * 256 + h * 8;

        // pass 1: scores
        float s[4] = {0.f, 0.f, 0.f, 0.f};
        #pragma unroll
        for (int j = 0; j < 8; ++j) {
            #pragma unroll
            for (int tk = 0; tk < 4; ++tk) {
                float4v c = SM4[kbase + tk * 64 + (j ^ h)];
                s[tk] += qc[j][0]*c[0] + qc[j][1]*c[1] + qc[j][2]*c[2] + qc[j][3]*c[3];
            }
        }
        #pragma unroll
        for (int tk = 0; tk < 4; ++tk) s[tk] *= 0.17677669529663687f;  // 1/sqrt(32)

        // softmax over 4
        float mx = fmaxf(fmaxf(s[0], s[1]), fmaxf(s[2], s[3]));
        float p[4];
        #pragma unroll
        for (int tk = 0; tk < 4; ++tk) p[tk] = __expf(s[tk] - mx);
        const float inv = 1.f / (p[0] + p[1] + p[2] + p[3]);
        #pragma unroll
        for (int tk = 0; tk < 4; ++tk) p[tk] *= inv;

        // pass 2: o = residual(q) + P·V
        float o[32];
        #pragma unroll
        for (int j = 0; j < 8; ++j)
            #pragma unroll
            for (int e = 0; e < 4; ++e) o[j * 4 + e] = qc[j][e];
        #pragma unroll
        for (int tk = 0; tk < 4; ++tk) {
            const float pj = p[tk];
            #pragma unroll
            for (int j = 0; j < 8; ++j) {
                float4v c = SM4[kbase + tk * 64 + (j ^ h)];
                #pragma unroll
                for (int e = 0; e < 4; ++e) o[j * 4 + e] += pj * c[e];
            }
        }

        // LayerNorm stats over 256 ch: reduce across the 8 head-lanes
        float sum = 0.f, sq = 0.f;
        #pragma unroll
        for (int c = 0; c < 32; ++c) { sum += o[c]; sq += o[c] * o[c]; }
        #pragma unroll
        for (int off = 1; off < 8; off <<= 1) {
            sum += __shfl_xor(sum, off, 64);
            sq  += __shfl_xor(sq,  off, 64);
        }
        const float mu  = sum * (1.f / 256.f);
        const float var = sq * (1.f / 256.f) - mu * mu;
        const float rs  = rsqrtf(var + 1e-5f);

        // epilogue: LN affine + strided stores (clean-write proven in round 0)
        float* op = out + rowoff * 4 + (size_t)(v << 8) + (size_t)(h << 5);
        #pragma unroll
        for (int j = 0; j < 8; ++j) {
            float4v wv = *(const float4v*)(lwr + j * 4);
            float4v bv = *(const float4v*)(lbr + j * 4);
            float4v ov;
            #pragma unroll
            for (int e = 0; e < 4; ++e)
                ov[e] = (o[j * 4 + e] - mu) * rs * wv[e] + bv[e];
            *(float4v*)(op + j * 4) = ov;
        }

        // WAR barrier: next iteration's issue() overwrites buf[cur]; both
        // waves' LDS reads are complete past this point.
        if (it < 3) {
            __builtin_amdgcn_s_barrier();
            __builtin_amdgcn_sched_barrier(0);
        }
        cur ^= 1;
    }
}

extern "C" void kernel_launch(void* const* d_in, const int* in_sizes, int n_in,
                              void* d_out, int out_size, void* d_ws, size_t ws_size,
                              hipStream_t stream) {
    (void)in_sizes; (void)n_in; (void)d_ws; (void)ws_size; (void)out_size;
    const float* rr = (const float*)d_in[0];
    const float* gg = (const float*)d_in[1];
    const float* bb = (const float*)d_in[2];
    const float* ii = (const float*)d_in[3];
    const float* w0 = (const float*)d_in[4];
    const float* b0 = (const float*)d_in[5];
    const float* w1 = (const float*)d_in[6];
    const float* b1 = (const float*)d_in[7];
    const float* w2 = (const float*)d_in[8];
    const float* b2 = (const float*)d_in[9];
    const float* w3 = (const float*)d_in[10];
    const float* b3 = (const float*)d_in[11];
    float* out = (float*)d_out;

    cattn_kernel<<<NBLK, 128, 0, stream>>>(rr, gg, bb, ii,
                                           w0, b0, w1, b1, w2, b2, w3, b3, out);
}

// Round 7
// 255.009 us; speedup vs baseline: 1.2176x; 1.2176x over previous
//
#include <hip/hip_runtime.h>

typedef __attribute__((ext_vector_type(4))) float float4v;

#define NBLK  1024
#define NITER 8

// Persistent 1024 blocks x 128 threads, 8 windows each, double-buffered LDS
// staging via global_load_lds (16B lanes). Exactly 4 blocks/CU (LDS cap 5) ->
// ALL blocks co-resident, no dispatch queue, no tail.
// Ledger (round-4-verified): issue(next) BEFORE the wait, s_waitcnt vmcnt(8)
// keeps ONLY the 8 newest prefetch loads outstanding and drains everything
// older (current staging + prev stores). NEVER leave stores in the kept
// window: store retirement is not ordered w.r.t. loads (round-6 failure).
// Epilogue transpose scratch is RACE-FREE by construction: wave 0 uses the
// r-region (chunks 0..255), wave 1 the ir-region (768..1023) of buf[cur] --
// regions no other wave ever reads -- in two half-passes (src lanes h<4, h>=4).
__global__ __launch_bounds__(128) void cattn_kernel(
    const float* __restrict__ rr, const float* __restrict__ gg,
    const float* __restrict__ bb, const float* __restrict__ ii,
    const float* __restrict__ w0, const float* __restrict__ b0,
    const float* __restrict__ w1, const float* __restrict__ b1,
    const float* __restrict__ w2, const float* __restrict__ b2,
    const float* __restrict__ w3, const float* __restrict__ b3,
    float* __restrict__ out)
{
    __shared__ float sm[2 * 4096];           // two 16 KB window buffers
    float4v* SM4 = (float4v*)sm;

    const int t   = threadIdx.x;
    const int wvi = t >> 6;                  // wave 0/1
    const int l   = t & 63;
    const int c4g = l ^ ((l >> 3) & 7);      // swizzled global chunk for staging

    // compute-lane mapping
    const int vloc = l >> 5;
    const int v    = (wvi << 1) | vloc;      // variant 0..3
    const int tok  = (l >> 3) & 3;           // query token 0..3
    const int h    = l & 7;                  // head 0..7
    const int grp  = l >> 3;                 // group within wave = vloc*4+tok
    const int kvt  = (v == 3) ? 1 : (v + 1); // kv tensor: g,b,ir,g (K==V)

    // hoisted LN params, transposed indexing: store j covers ch j*32+h*4..+4
    const float* lwr = (v & 2) ? ((v & 1) ? w3 : w2) : ((v & 1) ? w1 : w0);
    const float* lbr = (v & 2) ? ((v & 1) ? b3 : b2) : ((v & 1) ? b1 : b0);
    float4v wp[8], bp[8];
    #pragma unroll
    for (int j = 0; j < 8; ++j) {
        wp[j] = *(const float4v*)(lwr + j * 32 + h * 4);
        bp[j] = *(const float4v*)(lbr + j * 32 + h * 4);
    }

    const float* srcs[4] = { rr, gg, bb, ii };

    // async stage one window (16 KB) into LDS buffer `buf`: 8 loads per wave
    auto issue = [&](int buf, int wid) {
        const int bi  = wid >> 10;
        const int rem = wid & 1023;
        const int y0  = (rem >> 5) << 1;
        const int x0  = (rem & 31) << 1;
        #pragma unroll
        for (int kk = 0; kk < 8; ++kk) {
            // tensor = kk>>1 (CT), dy = kk&1 (CT), dx = wvi (wave-uniform)
            const float* g = srcs[kk >> 1]
                + (((size_t)(bi * 64 + y0 + (kk & 1))) * 64 + (size_t)(x0 + wvi)) * 256
                + (size_t)(c4g << 2);
            float* ldst = sm + buf * 4096 + (((kk << 1) | wvi) << 8);
            __builtin_amdgcn_global_load_lds(
                (const __attribute__((address_space(1))) void*)g,
                (__attribute__((address_space(3))) void*)ldst,
                16, 0, 0);
        }
    };

    int wid = blockIdx.x;                    // 8 windows: wid + k*1024
    issue(0, wid);
    int cur = 0;

    #pragma unroll 2
    for (int it = 0; it < NITER; ++it, wid += NBLK) {
        // issue the prefetch FIRST, then wait keeping exactly those 8 loads
        // outstanding: drains current staging + params + prev stores (all
        // older), independent of store-retirement order.
        if (it < NITER - 1) {
            issue(cur ^ 1, wid + NBLK);
            asm volatile("s_waitcnt vmcnt(8)" ::: "memory");
        } else {
            asm volatile("s_waitcnt vmcnt(0)" ::: "memory");
        }
        __builtin_amdgcn_s_barrier();        // both waves' staging arrived
        __builtin_amdgcn_sched_barrier(0);

        // ---------- compute window `wid` from buf[cur] ----------
        const int bi  = wid >> 10;
        const int rem = wid & 1023;
        const int y0  = (rem >> 5) << 1;
        const int x0  = (rem & 31) << 1;

        const int bb4   = cur << 10;                       // buf offset in chunks
        const int qbase = bb4 + v * 256 + tok * 64 + h * 8;
        const int kbase = bb4 + kvt * 256 + h * 8;

        // q fragment (also the residual)
        float q[32];
        #pragma unroll
        for (int j = 0; j < 8; ++j) {
            float4v c = SM4[qbase + (j ^ h)];
            #pragma unroll
            for (int e = 0; e < 4; ++e) q[j * 4 + e] = c[e];
        }

        // pass 1: scores
        float s[4] = {0.f, 0.f, 0.f, 0.f};
        #pragma unroll
        for (int j = 0; j < 8; ++j) {
            #pragma unroll
            for (int tk = 0; tk < 4; ++tk) {
                float4v c = SM4[kbase + tk * 64 + (j ^ h)];
                s[tk] += q[j*4+0]*c[0] + q[j*4+1]*c[1] + q[j*4+2]*c[2] + q[j*4+3]*c[3];
            }
        }
        #pragma unroll
        for (int tk = 0; tk < 4; ++tk) s[tk] *= 0.17677669529663687f;  // 1/sqrt(32)

        // softmax over 4
        float mx = fmaxf(fmaxf(s[0], s[1]), fmaxf(s[2], s[3]));
        float p[4];
        #pragma unroll
        for (int tk = 0; tk < 4; ++tk) p[tk] = __expf(s[tk] - mx);
        const float inv = 1.f / (p[0] + p[1] + p[2] + p[3]);
        #pragma unroll
        for (int tk = 0; tk < 4; ++tk) p[tk] *= inv;

        // pass 2: o = residual(q) + P·V
        float o[32];
        #pragma unroll
        for (int c = 0; c < 32; ++c) o[c] = q[c];
        #pragma unroll
        for (int tk = 0; tk < 4; ++tk) {
            const float pj = p[tk];
            #pragma unroll
            for (int j = 0; j < 8; ++j) {
                float4v c = SM4[kbase + tk * 64 + (j ^ h)];
                #pragma unroll
                for (int e = 0; e < 4; ++e) o[j * 4 + e] += pj * c[e];
            }
        }

        // LayerNorm stats over 256 ch: reduce across the 8 head-lanes
        float sum = 0.f, sq = 0.f;
        #pragma unroll
        for (int c = 0; c < 32; ++c) { sum += o[c]; sq += o[c] * o[c]; }
        #pragma unroll
        for (int off = 1; off < 8; off <<= 1) {
            sum += __shfl_xor(sum, off, 64);
            sq  += __shfl_xor(sq,  off, 64);
        }
        const float mu  = sum * (1.f / 256.f);
        const float var = sq * (1.f / 256.f) - mu * mu;
        const float rs  = rsqrtf(var + 1e-5f);

        // ---- full-line epilogue: half-pass transpose through PRIVATE scratch
        //      (wave 0: r-region chunks 0..255; wave 1: ir-region 768..1023 --
        //       no other wave reads these regions, so no cross-wave WAR) ----
        const int priv = bb4 + (wvi ? 768 : 0) + (grp << 5);  // 32 chunks/group

        const int dy = tok >> 1, dx = tok & 1;
        float* op = out
            + ((size_t)(bi * 64 + y0 + dy) * 64 + (size_t)(x0 + dx)) * 1024
            + (size_t)(v << 8);

        // pass A: output chunks j=0..3 (source lanes h<4 write their 8 regs)
        if (h < 4) {
            #pragma unroll
            for (int j = 0; j < 8; ++j) {
                float4v c;
                #pragma unroll
                for (int e = 0; e < 4; ++e) c[e] = o[j * 4 + e];
                SM4[priv + h * 8 + (j ^ h)] = c;
            }
        }
        asm volatile("s_waitcnt lgkmcnt(0)" ::: "memory");
        __builtin_amdgcn_sched_barrier(0);
        #pragma unroll
        for (int j = 0; j < 4; ++j) {
            float4v c = SM4[priv + j * 8 + (h ^ j)];   // lane j's o_h
            float4v ov;
            #pragma unroll
            for (int e = 0; e < 4; ++e)
                ov[e] = (c[e] - mu) * rs * wp[j][e] + bp[j][e];
            *(float4v*)(op + j * 32 + h * 4) = ov;
        }

        // pass B: output chunks j=4..7 (source lanes h>=4). Reads above were
        // issued first; per-wave DS ordering + alias analysis keep WAR safe.
        if (h >= 4) {
            #pragma unroll
            for (int j = 0; j < 8; ++j) {
                float4v c;
                #pragma unroll
                for (int e = 0; e < 4; ++e) c[e] = o[j * 4 + e];
                SM4[priv + (h - 4) * 8 + (j ^ h)] = c;
            }
        }
        asm volatile("s_waitcnt lgkmcnt(0)" ::: "memory");
        __builtin_amdgcn_sched_barrier(0);
        #pragma unroll
        for (int j = 4; j < 8; ++j) {
            float4v c = SM4[priv + (j - 4) * 8 + (h ^ j)];   // lane j's o_h
            float4v ov;
            #pragma unroll
            for (int e = 0; e < 4; ++e)
                ov[e] = (c[e] - mu) * rs * wp[j][e] + bp[j][e];
            *(float4v*)(op + j * 32 + h * 4) = ov;
        }

        // WAR barrier: next iteration's issue() overwrites buf[cur]; all
        // waves' LDS reads (compute + scratch) are complete past this point.
        if (it < NITER - 1) __builtin_amdgcn_s_barrier();
        cur ^= 1;
    }
}

extern "C" void kernel_launch(void* const* d_in, const int* in_sizes, int n_in,
                              void* d_out, int out_size, void* d_ws, size_t ws_size,
                              hipStream_t stream) {
    (void)in_sizes; (void)n_in; (void)d_ws; (void)ws_size; (void)out_size;
    const float* rr = (const float*)d_in[0];
    const float* gg = (const float*)d_in[1];
    const float* bb = (const float*)d_in[2];
    const float* ii = (const float*)d_in[3];
    const float* w0 = (const float*)d_in[4];
    const float* b0 = (const float*)d_in[5];
    const float* w1 = (const float*)d_in[6];
    const float* b1 = (const float*)d_in[7];
    const float* w2 = (const float*)d_in[8];
    const float* b2 = (const float*)d_in[9];
    const float* w3 = (const float*)d_in[10];
    const float* b3 = (const float*)d_in[11];
    float* out = (float*)d_out;

    cattn_kernel<<<NBLK, 128, 0, stream>>>(rr, gg, bb, ii,
                                           w0, b0, w1, b1, w2, b2, w3, b3, out);
}